// Round 1
// 562.868 us; speedup vs baseline: 1.0876x; 1.0876x over previous
//
#include <hip/hip_runtime.h>
#include <cstdint>
#include <cstddef>

// ---------------------------------------------------------------------------
// QuantCrossAttention, MI355X/gfx950.  B=2 N=4096 L=512 C=2048 H=16 D=128.
// - int8 quant replicated bit-exactly (IEEE div, rintf=RNE, max-chain)
// - w8a8 GEMMs on TRUE i8 MFMA (mfma_i32_16x16x64_i8), operands XOR-swizzled
//   in GLOBAL layout so global_load_lds stages verbatim.
// - fp32 GEMMs (K/V proj, QK^T, PV) via bf16 hi/lo split, 3 MFMA terms
// - attention: 512 thr, 16 rows/wave, MAX-FREE softmax.
// R6 changes (theory: exposed global-load latency in staging phases):
//   * attn_k: T14 issue-early/write-late staging — K/V^T/mask for chunk i+1
//     prefetched into regs during compute of chunk i; loop top only ds_writes
//     already-landed regs.  + T5 s_setprio(1) around QK/PV MFMA clusters.
//   * gemm_i8: minimum 2-phase double-buffered gl_lds16 pipeline (stage next
//     buffer before compute; ONE barrier per K-step; vmcnt drained by barrier).
// ---------------------------------------------------------------------------

typedef __bf16 bf16;
typedef __bf16 bf16x8 __attribute__((ext_vector_type(8)));
typedef __bf16 bf16x4 __attribute__((ext_vector_type(4)));
typedef float  f32x4  __attribute__((ext_vector_type(4)));
typedef int    i32x4  __attribute__((ext_vector_type(4)));

#define DEV __device__ __forceinline__

static constexpr int CB = 2;
static constexpr int CN = 4096;
static constexpr int CL = 512;
static constexpr int CC = 2048;
static constexpr int CH = 16;
static constexpr int CD = 128;
static constexpr int TOK = CB * CN;  // 8192 tokens
static constexpr int LR  = CB * CL;  // 1024 cond rows

DEV void gl_lds16(const void* g, void* l) {
  __builtin_amdgcn_global_load_lds(
      (const __attribute__((address_space(1))) unsigned int*)g,
      (__attribute__((address_space(3))) unsigned int*)l, 16, 0, 0);
}

DEV f32x4 mfma16(bf16x8 a, bf16x8 b, f32x4 c) {
  return __builtin_amdgcn_mfma_f32_16x16x32_bf16(a, b, c, 0, 0, 0);
}

DEV i32x4 mfma_i8(i32x4 a, i32x4 b, i32x4 c) {
  return __builtin_amdgcn_mfma_i32_16x16x64_i8(a, b, c, 0, 0, 0);
}

// --------- per-row symmetric int8 quant -> swizzled int8 + scale ------------
// Output layout: within each 64B k-block, 16B unit u placed at u ^ ((row>>1)&3)
// (matches gemm_i8's LDS fragment-read swizzle; 2-way LDS = free).
__global__ __launch_bounds__(256) void quant_rows_i8(
    const float* __restrict__ in, signed char* __restrict__ q,
    float* __restrict__ scale)
{
  const int r = blockIdx.x, t = threadIdx.x;
  const float* x = in + (size_t)r * CC;
  const float4 v0 = ((const float4*)x)[2 * t];
  const float4 v1 = ((const float4*)x)[2 * t + 1];
  float m = fmaxf(fmaxf(fmaxf(fabsf(v0.x), fabsf(v0.y)), fmaxf(fabsf(v0.z), fabsf(v0.w))),
                  fmaxf(fmaxf(fabsf(v1.x), fabsf(v1.y)), fmaxf(fabsf(v1.z), fabsf(v1.w))));
#pragma unroll
  for (int off = 32; off > 0; off >>= 1) m = fmaxf(m, __shfl_xor(m, off));
  __shared__ float sm[4];
  if ((t & 63) == 0) sm[t >> 6] = m;
  __syncthreads();
  m = fmaxf(fmaxf(sm[0], sm[1]), fmaxf(sm[2], sm[3]));
  const float s = fmaxf(m / 127.0f, 1e-8f);   // IEEE divide: bit-matches np
  if (t == 0) scale[r] = s;
  const float a[8] = {v0.x, v0.y, v0.z, v0.w, v1.x, v1.y, v1.z, v1.w};
  int2 pk;
  int lo = 0, hi = 0;
#pragma unroll
  for (int j = 0; j < 4; j++) {
    const int b0 = (int)fminf(fmaxf(rintf(a[j]     / s), -127.f), 127.f);
    const int b1 = (int)fminf(fmaxf(rintf(a[4 + j] / s), -127.f), 127.f);
    lo |= (b0 & 255) << (8 * j);
    hi |= (b1 & 255) << (8 * j);
  }
  pk.x = lo; pk.y = hi;
  const int c0 = t * 8;
  const int f = (r >> 1) & 3;
  const int pos = (c0 & ~63) | ((((c0 >> 4) & 3) ^ f) << 4) | (c0 & 15);
  *(int2*)&q[(size_t)r * CC + pos] = pk;
}

// --------- fp32 -> bf16 hi/lo split ----------------------------------------
__global__ __launch_bounds__(256) void split_pair_k(
    const float* __restrict__ in, bf16* __restrict__ hi, bf16* __restrict__ lo)
{
  const size_t i = (size_t)blockIdx.x * 256 + threadIdx.x;  // float4 index
  const float4 v = ((const float4*)in)[i];
  const float a[4] = {v.x, v.y, v.z, v.w};
  bf16x4 h4, l4;
#pragma unroll
  for (int j = 0; j < 4; j++) {
    bf16 h = (bf16)a[j];
    h4[j] = h;
    l4[j] = (bf16)(a[j] - (float)h);
  }
  ((bf16x4*)hi)[i] = h4;
  ((bf16x4*)lo)[i] = l4;
}

// --------- (x + bias[col]) -> bf16 hi/lo split (K path) ---------------------
__global__ __launch_bounds__(256) void bias_split_k(
    const float* __restrict__ in, const float* __restrict__ bias,
    bf16* __restrict__ hi, bf16* __restrict__ lo)
{
  const size_t i = (size_t)blockIdx.x * 256 + threadIdx.x;  // float4 index
  const float4 v = ((const float4*)in)[i];
  const float4 bb = ((const float4*)bias)[i & (CC / 4 - 1)];
  const float a[4] = {v.x + bb.x, v.y + bb.y, v.z + bb.z, v.w + bb.w};
  bf16x4 h4, l4;
#pragma unroll
  for (int j = 0; j < 4; j++) {
    bf16 h = (bf16)a[j];
    h4[j] = h;
    l4[j] = (bf16)(a[j] - (float)h);
  }
  ((bf16x4*)hi)[i] = h4;
  ((bf16x4*)lo)[i] = l4;
}

// --------- (V + bias) -> transpose to [b,h,d,l] -> bf16 hi/lo split ---------
__global__ __launch_bounds__(256) void bias_split_vt_k(
    const float* __restrict__ Vf, const float* __restrict__ bias,
    bf16* __restrict__ vth, bf16* __restrict__ vtl)
{
  __shared__ float tile[32][33];
  const int t = threadIdx.x;
  const int l0 = blockIdx.x * 32, d0 = blockIdx.y * 32, bh = blockIdx.z;
  const int b = bh >> 4, h = bh & 15;
  const int r = t >> 3, c4 = (t & 7) * 4;
  const float4 v = *(const float4*)&Vf[((size_t)b * CL + l0 + r) * CC + h * CD + d0 + c4];
  const float4 bb = *(const float4*)&bias[h * CD + d0 + c4];
  tile[r][c4 + 0] = v.x + bb.x;
  tile[r][c4 + 1] = v.y + bb.y;
  tile[r][c4 + 2] = v.z + bb.z;
  tile[r][c4 + 3] = v.w + bb.w;
  __syncthreads();
  bf16x4 h4, l4;
#pragma unroll
  for (int j = 0; j < 4; j++) {
    const float a = tile[c4 + j][r];   // transposed read, pad-33 => <=2-way
    const bf16 hh = (bf16)a;
    h4[j] = hh;
    l4[j] = (bf16)(a - (float)hh);
  }
  const size_t o = ((size_t)bh * CD + d0 + r) * CL + l0 + c4;
  *(bf16x4*)&vth[o] = h4;
  *(bf16x4*)&vtl[o] = l4;
}

// --------- int8 GEMM, A[M,K] * B[Nd,K]^T, both K-major, pre-swizzled --------
// MODE: 0 = fp32 out w/ dequant+bias;  1 = dequant+bias then split hi/lo bf16
// R6: 2-phase double-buffered pipeline — stage buf^1 for k+64 BEFORE compute
// of buf; ONE __syncthreads per K-step (drains vmcnt+lgkm: next buffer landed
// AND all frag reads of current buffer done before it is overwritten).
template <int MODE>
__global__ __launch_bounds__(256) void gemm_i8(
    const signed char* __restrict__ A, const signed char* __restrict__ B,
    float* __restrict__ out0, bf16* __restrict__ outH, bf16* __restrict__ outL,
    const float* __restrict__ rowS, const float* __restrict__ colS,
    const float* __restrict__ bias, const int Nd, const int K)
{
  __shared__ signed char sA[2][128 * 64] __attribute__((aligned(16)));
  __shared__ signed char sB[2][128 * 64] __attribute__((aligned(16)));
  const int t = threadIdx.x;
  const int m0 = blockIdx.y * 128, n0 = blockIdx.x * 128;
  const int srow = t >> 2, scol = (t & 3) * 16;   // 64 rows/instr, 16B/lane
  const signed char* aP = A + (size_t)(m0 + srow) * K + scol;
  const signed char* bP = B + (size_t)(n0 + srow) * K + scol;
  const int lane = t & 63, wave = t >> 6;
  const int wm = (wave >> 1) * 64, wn = (wave & 1) * 64;
  const int quad = lane >> 4, l16 = lane & 15;
  i32x4 acc[4][4] = {};

  // prologue: stage k-block 0 into buffer 0
  gl_lds16(aP,                  &sA[0][t * 16]);
  gl_lds16(aP + (size_t)64 * K, &sA[0][4096 + t * 16]);
  gl_lds16(bP,                  &sB[0][t * 16]);
  gl_lds16(bP + (size_t)64 * K, &sB[0][4096 + t * 16]);
  __syncthreads();

  int cur = 0;
  for (int kb = 0; kb < K; kb += 64) {
    const int nx = kb + 64;
    if (nx < K) {   // stage next k-block into the other buffer (async)
      gl_lds16(aP + nx,                  &sA[cur ^ 1][t * 16]);
      gl_lds16(aP + nx + (size_t)64 * K, &sA[cur ^ 1][4096 + t * 16]);
      gl_lds16(bP + nx,                  &sB[cur ^ 1][t * 16]);
      gl_lds16(bP + nx + (size_t)64 * K, &sB[cur ^ 1][4096 + t * 16]);
    }
    i32x4 fa[4], fb[4];
#pragma unroll
    for (int i = 0; i < 4; i++) {
      const int ra = wm + i * 16 + l16;
      const int rb = wn + i * 16 + l16;
      fa[i] = *(const i32x4*)&sA[cur][ra * 64 + (quad ^ ((ra >> 1) & 3)) * 16];
      fb[i] = *(const i32x4*)&sB[cur][rb * 64 + (quad ^ ((rb >> 1) & 3)) * 16];
    }
#pragma unroll
    for (int mt = 0; mt < 4; mt++)
#pragma unroll
      for (int nt = 0; nt < 4; nt++)
        acc[mt][nt] = mfma_i8(fa[mt], fb[nt], acc[mt][nt]);
    __syncthreads();   // drains vmcnt(0): buf^1 staged; lgkm: buf reads done
    cur ^= 1;
  }

  // epilogue: C/D layout col=lane&15, row=quad*4+reg (shape-determined)
#pragma unroll
  for (int mt = 0; mt < 4; mt++)
#pragma unroll
    for (int nt = 0; nt < 4; nt++)
#pragma unroll
      for (int rg = 0; rg < 4; rg++) {
        const int mr = m0 + wm + mt * 16 + quad * 4 + rg;
        const int nc = n0 + wn + nt * 16 + l16;
        const float a = (float)acc[mt][nt][rg];
        const float sc = rowS[mr] * colS[nc];   // (sx*sw) first: matches np
        const float v = a * sc + bias[nc];
        if (MODE == 0) {
          out0[(size_t)mr * Nd + nc] = v;
        } else {
          const bf16 h = (bf16)v;
          outH[(size_t)mr * Nd + nc] = h;
          outL[(size_t)mr * Nd + nc] = (bf16)(v - (float)h);
        }
      }
}

// --------- bf16-split GEMM (K/V projections only) ---------------------------
// TERMS=3 hi/lo split (fp32 emulation), MODE=2 atomic split-K, FUSEKV
__global__ __launch_bounds__(256) void gemm_kv(
    const bf16* __restrict__ Ah, const bf16* __restrict__ Al,
    const bf16* __restrict__ B0h, const bf16* __restrict__ B0l,
    const bf16* __restrict__ B1h, const bf16* __restrict__ B1l,
    float* __restrict__ out0, float* __restrict__ out1,
    const int Nd, const int K, const int kLen)
{
  __shared__ bf16 sAh[128 * 32] __attribute__((aligned(16)));
  __shared__ bf16 sBh[128 * 32] __attribute__((aligned(16)));
  __shared__ bf16 sAl[128 * 32] __attribute__((aligned(16)));
  __shared__ bf16 sBl[128 * 32] __attribute__((aligned(16)));
  const int t = threadIdx.x;
  const int kv = blockIdx.z >> 2, chunk = blockIdx.z & 3;
  const bf16* Bh = kv ? B1h : B0h;
  const bf16* Bl = kv ? B1l : B0l;
  float* outF = kv ? out1 : out0;
  const int m0 = blockIdx.y * 128, n0 = blockIdx.x * 128;
  const int k0 = chunk * kLen;
  const int srow = t >> 2, scol = (t & 3) * 8;
  const bf16* aP  = Ah + (size_t)(m0 + srow) * K + k0 + scol;
  const bf16* bP  = Bh + (size_t)(n0 + srow) * K + k0 + scol;
  const bf16* aPl = Al + (size_t)(m0 + srow) * K + k0 + scol;
  const bf16* bPl = Bl + (size_t)(n0 + srow) * K + k0 + scol;
  const int lane = t & 63, wave = t >> 6;
  const int wm = (wave >> 1) * 64, wn = (wave & 1) * 64;
  const int quad = lane >> 4, l16 = lane & 15;
  f32x4 acc[4][4] = {};

  for (int kb = 0; kb < kLen; kb += 32) {
    __syncthreads();
    gl_lds16(aP + kb,                   &sAh[t * 8]);
    gl_lds16(aP + kb + (size_t)64 * K,  &sAh[2048 + t * 8]);
    gl_lds16(bP + kb,                   &sBh[t * 8]);
    gl_lds16(bP + kb + (size_t)64 * K,  &sBh[2048 + t * 8]);
    gl_lds16(aPl + kb,                  &sAl[t * 8]);
    gl_lds16(aPl + kb + (size_t)64 * K, &sAl[2048 + t * 8]);
    gl_lds16(bPl + kb,                  &sBl[t * 8]);
    gl_lds16(bPl + kb + (size_t)64 * K, &sBl[2048 + t * 8]);
    __syncthreads();
    bf16x8 fa[4], fb[4], fal[4], fbl[4];
#pragma unroll
    for (int i = 0; i < 4; i++) {
      fa[i]  = *(const bf16x8*)&sAh[(wm + i * 16 + l16) * 32 + quad * 8];
      fb[i]  = *(const bf16x8*)&sBh[(wn + i * 16 + l16) * 32 + quad * 8];
      fal[i] = *(const bf16x8*)&sAl[(wm + i * 16 + l16) * 32 + quad * 8];
      fbl[i] = *(const bf16x8*)&sBl[(wn + i * 16 + l16) * 32 + quad * 8];
    }
#pragma unroll
    for (int mt = 0; mt < 4; mt++)
#pragma unroll
      for (int nt = 0; nt < 4; nt++) {
        f32x4 c = acc[mt][nt];
        c = mfma16(fa[mt],  fb[nt],  c);
        c = mfma16(fa[mt],  fbl[nt], c);
        c = mfma16(fal[mt], fb[nt],  c);
        acc[mt][nt] = c;
      }
  }

#pragma unroll
  for (int mt = 0; mt < 4; mt++)
#pragma unroll
    for (int nt = 0; nt < 4; nt++)
#pragma unroll
      for (int rg = 0; rg < 4; rg++) {
        const int mr = m0 + wm + mt * 16 + quad * 4 + rg;
        const int nc = n0 + wn + nt * 16 + l16;
        atomicAdd(&outF[(size_t)mr * Nd + nc], acc[mt][nt][rg]);
      }
}

// --------- flash attention, split-bf16, MAX-FREE softmax --------------------
// block = 512 thr / 8 waves / 128 Q rows; wave owns 16 rows (R3 config).
// R6: T14 staging — next chunk's K/V^T/mask prefetched into registers during
// compute of current chunk; loop top only ds_writes landed registers (the
// vmcnt wait the compiler inserts there is ~free: loads issued a full compute
// phase earlier).  T5: setprio(1) around QK and PV MFMA clusters.
__global__ __launch_bounds__(512) void attn_k(
    const bf16* __restrict__ qh, const bf16* __restrict__ ql,
    const bf16* __restrict__ kh, const bf16* __restrict__ kl,
    const bf16* __restrict__ vth, const bf16* __restrict__ vtl,
    const float* __restrict__ mask, float* __restrict__ O)
{
  // arena: ks [2][32][136] (17408 B) | vt [2][128][40] (20480 B) | ps [8][16][36] (18432 B)
  __shared__ char arena[17408 + 20480 + 18432] __attribute__((aligned(16)));
  bf16 (*ks)[32][136] = (bf16 (*)[32][136])arena;
  bf16 (*vt)[128][40] = (bf16 (*)[128][40])(arena + 17408);
  float (*ps)[16][36] = (float (*)[16][36])(arena + 17408 + 20480);
  const int t = threadIdx.x, lane = t & 63, w = t >> 6;
  const int quad = lane >> 4, l16 = lane & 15;
  const int n0 = blockIdx.x * 128, h = blockIdx.y, b = blockIdx.z;
  const int bh = b * CH + h;
  const size_t qrow0 = (size_t)b * CN + n0;
  const float* mrow_base = mask + ((size_t)b * CN + n0 + w * 16 + quad * 4) * CL;

  // ---- staging-lane geometry + chunk-0 prefetch (overlaps Q staging) ----
  const int krow = t >> 4, ksg = t & 15;   // K: 32 l-rows x 128 d, 16B/lane
  const int vrow = t >> 2, vsg = t & 3;    // V^T: 128 d-rows x 32 l, 8B.. 16B/lane
  uint4 krh, krl, vrh, vrl;
  float mnx[2][4];
  {
    const size_t gro = ((size_t)b * CL + krow) * CC + h * CD + ksg * 8;
    krh = *(const uint4*)(kh + gro);
    krl = *(const uint4*)(kl + gro);
    const size_t gvo = ((size_t)bh * CD + vrow) * CL + vsg * 8;
    vrh = *(const uint4*)(vth + gvo);
    vrl = *(const uint4*)(vtl + gvo);
#pragma unroll
    for (int rg = 0; rg < 4; rg++) {
      const float* mrp = mrow_base + (size_t)rg * CL;
      mnx[0][rg] = mrp[l16];
      mnx[1][rg] = mrp[16 + l16];
    }
  }

  // ---- Q fragments into registers (staged via arena for coalescing) ----
  bf16x8 qfh[4], qfl[4];
  {
    bf16* qs = (bf16*)arena;   // 128 rows x 136 = 34816 B <= ks+vt extent
    const int row = t >> 2, sg = t & 3;
    {
      const bf16* src = qh + (qrow0 + row) * CC + h * CD + sg * 32;
      bf16* dst = qs + row * 136 + sg * 32;
#pragma unroll
      for (int j = 0; j < 4; j++) ((uint4*)dst)[j] = ((const uint4*)src)[j];
    }
    __syncthreads();
#pragma unroll
    for (int s = 0; s < 4; s++)
      qfh[s] = *(const bf16x8*)&qs[(w * 16 + l16) * 136 + s * 32 + quad * 8];
    __syncthreads();
    {
      const bf16* src = ql + (qrow0 + row) * CC + h * CD + sg * 32;
      bf16* dst = qs + row * 136 + sg * 32;
#pragma unroll
      for (int j = 0; j < 4; j++) ((uint4*)dst)[j] = ((const uint4*)src)[j];
    }
    __syncthreads();
#pragma unroll
    for (int s = 0; s < 4; s++)
      qfl[s] = *(const bf16x8*)&qs[(w * 16 + l16) * 136 + s * 32 + quad * 8];
  }

  f32x4 oacc[8] = {};
  f32x4 suma = {};          // row-sum accumulator (MFMA ones-trick)
  const bf16 one = (bf16)1.0f;
  const bf16x8 ones = {one, one, one, one, one, one, one, one};
  const float isd = 0.08838834764831845f;   // np.float32(1/sqrt(128))

  for (int lc = 0; lc < CL; lc += 32) {
    __syncthreads();   // prior chunk's frag reads done (buffers free)
    // ---- write-late: ds_write the prefetched (already landed) registers ---
    *(uint4*)&ks[0][krow][ksg * 8] = krh;
    *(uint4*)&ks[1][krow][ksg * 8] = krl;
    {
      const int vc = (vsg ^ ((vrow >> 3) & 3)) * 8;   // XOR chunk swizzle
      *(uint4*)&vt[0][vrow][vc] = vrh;
      *(uint4*)&vt[1][vrow][vc] = vrl;
    }
    float mcur[2][4];
#pragma unroll
    for (int rg = 0; rg < 4; rg++) {
      mcur[0][rg] = mnx[0][rg];
      mcur[1][rg] = mnx[1][rg];
    }
    __syncthreads();

    // ---- issue-early: prefetch chunk lc+32 (hides under QK/PV compute) ----
    const int lcn = lc + 32;
    if (lcn < CL) {
      const size_t gro = ((size_t)b * CL + lcn + krow) * CC + h * CD + ksg * 8;
      krh = *(const uint4*)(kh + gro);
      krl = *(const uint4*)(kl + gro);
      const size_t gvo = ((size_t)bh * CD + vrow) * CL + lcn + vsg * 8;
      vrh = *(const uint4*)(vth + gvo);
      vrl = *(const uint4*)(vtl + gvo);
#pragma unroll
      for (int rg = 0; rg < 4; rg++) {
        const float* mrp = mrow_base + (size_t)rg * CL + lcn;
        mnx[0][rg] = mrp[l16];
        mnx[1][rg] = mrp[16 + l16];
      }
    }

    // ---- S = Q K^T (split, 3 terms), two 16x16 l-tiles -------------------
    f32x4 sacc[2] = {};
    __builtin_amdgcn_s_setprio(1);
#pragma unroll
    for (int s = 0; s < 4; s++) {
#pragma unroll
      for (int lt = 0; lt < 2; lt++) {
        bf16x8 kbh = *(const bf16x8*)&ks[0][lt * 16 + l16][s * 32 + quad * 8];
        bf16x8 kbl = *(const bf16x8*)&ks[1][lt * 16 + l16][s * 32 + quad * 8];
        sacc[lt] = mfma16(qfh[s], kbh, sacc[lt]);
        sacc[lt] = mfma16(qfh[s], kbl, sacc[lt]);
        sacc[lt] = mfma16(qfl[s], kbh, sacc[lt]);
      }
    }
    __builtin_amdgcn_s_setprio(0);

    // ---- MAX-FREE softmax: u = exp(s*isd + mask); sum rides MFMA ---------
    float u[2][4];
#pragma unroll
    for (int rg = 0; rg < 4; rg++) {
      u[0][rg] = __expf(sacc[0][rg] * isd + mcur[0][rg]);
      u[1][rg] = __expf(sacc[1][rg] * isd + mcur[1][rg]);
    }

    // ---- P: C-layout -> A-layout via wave-private LDS round-trip ---------
#pragma unroll
    for (int lt = 0; lt < 2; lt++)
#pragma unroll
      for (int rg = 0; rg < 4; rg++)
        ps[w][quad * 4 + rg][lt * 16 + l16] = u[lt][rg];
    const float4 p0 = *(const float4*)&ps[w][l16][quad * 8];
    const float4 p1 = *(const float4*)&ps[w][l16][quad * 8 + 4];
    const float pv[8] = {p0.x, p0.y, p0.z, p0.w, p1.x, p1.y, p1.z, p1.w};
    bf16x8 ph, pl;
#pragma unroll
    for (int j = 0; j < 8; j++) {
      bf16 hh = (bf16)pv[j];
      ph[j] = hh;
      pl[j] = (bf16)(pv[j] - (float)hh);
    }

    // ---- O += P V (split, 3 terms) + row-sum channel ---------------------
    suma = mfma16(ph, ones, suma);
    suma = mfma16(pl, ones, suma);
    __builtin_amdgcn_s_setprio(1);
#pragma unroll
    for (int nt = 0; nt < 8; nt++) {
      const int vr = nt * 16 + l16;
      const int vsw = (quad ^ ((vr >> 3) & 3)) * 8;   // match staging swizzle
      bf16x8 vbh = *(const bf16x8*)&vt[0][vr][vsw];
      bf16x8 vbl = *(const bf16x8*)&vt[1][vr][vsw];
      f32x4 c = oacc[nt];
      c = mfma16(ph, vbh, c);
      c = mfma16(ph, vbl, c);
      c = mfma16(pl, vbh, c);
      oacc[nt] = c;
    }
    __builtin_amdgcn_s_setprio(0);
  }

  // ---- epilogue: O / sum ----------------------------------------------------
  f32x4 inv;
#pragma unroll
  for (int rg = 0; rg < 4; rg++) inv[rg] = 1.0f / suma[rg];
#pragma unroll
  for (int nt = 0; nt < 8; nt++)
#pragma unroll
    for (int rg = 0; rg < 4; rg++) {
      const size_t row = qrow0 + w * 16 + quad * 4 + rg;
      O[row * CC + h * CD + nt * 16 + l16] = oacc[nt][rg] * inv[rg];
    }
}

// ---------------------------------------------------------------------------
extern "C" void kernel_launch(void* const* d_in, const int* in_sizes, int n_in,
                              void* d_out, int out_size, void* d_ws, size_t ws_size,
                              hipStream_t stream)
{
  (void)in_sizes; (void)n_in; (void)out_size; (void)ws_size;
  const float* x    = (const float*)d_in[0];
  const float* cond = (const float*)d_in[1];
  const float* mask = (const float*)d_in[2];
  const float* wq   = (const float*)d_in[3];
  const float* bq   = (const float*)d_in[4];
  const float* wk   = (const float*)d_in[5];
  const float* bk   = (const float*)d_in[6];
  const float* wv   = (const float*)d_in[7];
  const float* bv   = (const float*)d_in[8];
  const float* wo   = (const float*)d_in[9];
  const float* bo   = (const float*)d_in[10];
  float* out = (float*)d_out;

  char* wsb = (char*)d_ws;
  size_t off = 0;
  auto alloc = [&](size_t bytes) -> char* {
    char* p = wsb + off;
    off += (bytes + 255) & ~(size_t)255;
    return p;
  };
  // Region 1 (dead before attention; Obuf 64 MiB aliases qx..Kf)
  signed char* qx  = (signed char*)alloc((size_t)TOK * CC);  // 16 MiB
  signed char* qwq = (signed char*)alloc((size_t)CC * CC);   //  4 MiB
  bf16* ch  = (bf16*)alloc((size_t)LR * CC * 2);   //  4 MiB
  bf16* cl_ = (bf16*)alloc((size_t)LR * CC * 2);   //  4 MiB
  bf16* wkh = (bf16*)alloc((size_t)CC * CC * 2);   //  8 MiB
  bf16* wkl = (bf16*)alloc((size_t)CC * CC * 2);   //  8 MiB
  bf16* wvh = (bf16*)alloc((size_t)CC * CC * 2);   //  8 MiB
  bf16* wvl = (bf16*)alloc((size_t)CC * CC * 2);   //  8 MiB
  float* Kf = (float*)alloc((size_t)LR * CC * 4);  //  8 MiB (split-K accum)
  float* Vf = (float*)alloc((size_t)LR * CC * 4);  //  8 MiB (contiguous after Kf)
  float* Obuf = (float*)qx;                        // alias: 64 MiB over qx..Kf
  // Region 2 (live through attention)
  bf16* qhb = (bf16*)alloc((size_t)TOK * CC * 2);  // 32 MiB (later reused as qO)
  bf16* qlb = (bf16*)alloc((size_t)TOK * CC * 2);  // 32 MiB
  bf16* khb = (bf16*)alloc((size_t)LR * CC * 2);
  bf16* klb = (bf16*)alloc((size_t)LR * CC * 2);
  bf16* vth = (bf16*)alloc((size_t)LR * CC * 2);   // V^T [b,h,d,l] hi
  bf16* vtl = (bf16*)alloc((size_t)LR * CC * 2);   // V^T [b,h,d,l] lo
  signed char* qwo = (signed char*)alloc((size_t)CC * CC);
  float* sx  = (float*)alloc((size_t)TOK * 4);
  float* swq = (float*)alloc((size_t)CC * 4);
  float* swo = (float*)alloc((size_t)CC * 4);
  float* sO  = (float*)alloc((size_t)TOK * 4);
  signed char* qO = (signed char*)qhb;   // alias: qh/ql dead after attention

  // 1) quantize weights and x (int8, swizzled for gemm_i8)
  quant_rows_i8<<<CC,  256, 0, stream>>>(wq, qwq, swq);
  quant_rows_i8<<<CC,  256, 0, stream>>>(wo, qwo, swo);
  quant_rows_i8<<<TOK, 256, 0, stream>>>(x, qx, sx);
  // 2) split fp32 inputs for the fp32-emulated GEMMs
  split_pair_k<<<(LR * CC / 4) / 256, 256, 0, stream>>>(cond, ch, cl_);
  split_pair_k<<<(CC * CC / 4) / 256, 256, 0, stream>>>(wk, wkh, wkl);
  split_pair_k<<<(CC * CC / 4) / 256, 256, 0, stream>>>(wv, wvh, wvl);
  // 3) Q = dequant(qx @ qwq^T) + bq, written as bf16 hi/lo split  (i8 MFMA)
  gemm_i8<1><<<dim3(CC / 128, TOK / 128, 1), 256, 0, stream>>>(
      qx, qwq, nullptr, qhb, qlb, sx, swq, bq, CC, CC);
  // 4) K/V projections: fused-KV + split-K x4 (atomic fp32 accum)
  (void)hipMemsetAsync(Kf, 0, (size_t)LR * CC * 4 * 2, stream);  // Kf+Vf contiguous
  gemm_kv<<<dim3(CC / 128, LR / 128, 8), 256, 0, stream>>>(
      ch, cl_, wkh, wkl, wvh, wvl, Kf, Vf, CC, CC, 512);
  bias_split_k<<<(LR * CC / 4) / 256, 256, 0, stream>>>(Kf, bk, khb, klb);
  bias_split_vt_k<<<dim3(CL / 32, CD / 32, CB * CH), 256, 0, stream>>>(Vf, bv, vth, vtl);
  // 5) attention: 128-row Q tiles, 512 threads, max-free softmax
  attn_k<<<dim3(CN / 128, CH, CB), 512, 0, stream>>>(
      qhb, qlb, khb, klb, vth, vtl, mask, Obuf);
  // 6) requant O (int8 swizzled), then output projection (i8 MFMA)
  quant_rows_i8<<<TOK, 256, 0, stream>>>(Obuf, qO, sO);
  gemm_i8<0><<<dim3(CC / 128, TOK / 128, 1), 256, 0, stream>>>(
      qO, qwo, out, nullptr, nullptr, sO, swo, bo, CC, CC);
}

// Round 2
// 548.225 us; speedup vs baseline: 1.1167x; 1.0267x over previous
//
#include <hip/hip_runtime.h>
#include <cstdint>
#include <cstddef>

// ---------------------------------------------------------------------------
// QuantCrossAttention, MI355X/gfx950.  B=2 N=4096 L=512 C=2048 H=16 D=128.
// - int8 quant replicated bit-exactly (IEEE div, rintf=RNE, max-chain)
// - w8a8 GEMMs on TRUE i8 MFMA (mfma_i32_16x16x64_i8), operands XOR-swizzled
//   in GLOBAL layout so global_load_lds stages verbatim.
// - fp32 GEMMs (K/V proj, QK^T, PV) via bf16 hi/lo split, 3 MFMA terms
// - attention: 512 thr, 16 rows/wave, MAX-FREE softmax.
// R6: T14 issue-early/write-late staging in attn; 2-phase dbuf in gemm_i8.
// R7 (theory: R6's +32 prefetch regs crossed the 128 total-VGPR boundary ->
//     1 block/CU (Occupancy 43->22).  Restore 2 blocks + L2 locality):
//   * attn_k: register diet — mask loaded per-chunk (no double-buffer; QK
//     covers its latency), K prefetch issued at chunk top, V prefetch issued
//     post-softmax (lifetimes staggered).  __launch_bounds__(512,4) enforces
//     the 128-reg cap => 2 resident blocks/CU.
//   * T1 XCD-aware block swizzle on attn_k / gemm_i8 / gemm_kv (all grids
//     1024 % 8 == 0 -> simple bijective form): per-XCD contiguous logical
//     ranges make shared operand panels L2-resident.
// ---------------------------------------------------------------------------

typedef __bf16 bf16;
typedef __bf16 bf16x8 __attribute__((ext_vector_type(8)));
typedef __bf16 bf16x4 __attribute__((ext_vector_type(4)));
typedef float  f32x4  __attribute__((ext_vector_type(4)));
typedef int    i32x4  __attribute__((ext_vector_type(4)));

#define DEV __device__ __forceinline__

static constexpr int CB = 2;
static constexpr int CN = 4096;
static constexpr int CL = 512;
static constexpr int CC = 2048;
static constexpr int CH = 16;
static constexpr int CD = 128;
static constexpr int TOK = CB * CN;  // 8192 tokens
static constexpr int LR  = CB * CL;  // 1024 cond rows

DEV void gl_lds16(const void* g, void* l) {
  __builtin_amdgcn_global_load_lds(
      (const __attribute__((address_space(1))) unsigned int*)g,
      (__attribute__((address_space(3))) unsigned int*)l, 16, 0, 0);
}

DEV f32x4 mfma16(bf16x8 a, bf16x8 b, f32x4 c) {
  return __builtin_amdgcn_mfma_f32_16x16x32_bf16(a, b, c, 0, 0, 0);
}

DEV i32x4 mfma_i8(i32x4 a, i32x4 b, i32x4 c) {
  return __builtin_amdgcn_mfma_i32_16x16x64_i8(a, b, c, 0, 0, 0);
}

// --------- per-row symmetric int8 quant -> swizzled int8 + scale ------------
// Output layout: within each 64B k-block, 16B unit u placed at u ^ ((row>>1)&3)
// (matches gemm_i8's LDS fragment-read swizzle; 2-way LDS = free).
__global__ __launch_bounds__(256) void quant_rows_i8(
    const float* __restrict__ in, signed char* __restrict__ q,
    float* __restrict__ scale)
{
  const int r = blockIdx.x, t = threadIdx.x;
  const float* x = in + (size_t)r * CC;
  const float4 v0 = ((const float4*)x)[2 * t];
  const float4 v1 = ((const float4*)x)[2 * t + 1];
  float m = fmaxf(fmaxf(fmaxf(fabsf(v0.x), fabsf(v0.y)), fmaxf(fabsf(v0.z), fabsf(v0.w))),
                  fmaxf(fmaxf(fabsf(v1.x), fabsf(v1.y)), fmaxf(fabsf(v1.z), fabsf(v1.w))));
#pragma unroll
  for (int off = 32; off > 0; off >>= 1) m = fmaxf(m, __shfl_xor(m, off));
  __shared__ float sm[4];
  if ((t & 63) == 0) sm[t >> 6] = m;
  __syncthreads();
  m = fmaxf(fmaxf(sm[0], sm[1]), fmaxf(sm[2], sm[3]));
  const float s = fmaxf(m / 127.0f, 1e-8f);   // IEEE divide: bit-matches np
  if (t == 0) scale[r] = s;
  const float a[8] = {v0.x, v0.y, v0.z, v0.w, v1.x, v1.y, v1.z, v1.w};
  int2 pk;
  int lo = 0, hi = 0;
#pragma unroll
  for (int j = 0; j < 4; j++) {
    const int b0 = (int)fminf(fmaxf(rintf(a[j]     / s), -127.f), 127.f);
    const int b1 = (int)fminf(fmaxf(rintf(a[4 + j] / s), -127.f), 127.f);
    lo |= (b0 & 255) << (8 * j);
    hi |= (b1 & 255) << (8 * j);
  }
  pk.x = lo; pk.y = hi;
  const int c0 = t * 8;
  const int f = (r >> 1) & 3;
  const int pos = (c0 & ~63) | ((((c0 >> 4) & 3) ^ f) << 4) | (c0 & 15);
  *(int2*)&q[(size_t)r * CC + pos] = pk;
}

// --------- fp32 -> bf16 hi/lo split ----------------------------------------
__global__ __launch_bounds__(256) void split_pair_k(
    const float* __restrict__ in, bf16* __restrict__ hi, bf16* __restrict__ lo)
{
  const size_t i = (size_t)blockIdx.x * 256 + threadIdx.x;  // float4 index
  const float4 v = ((const float4*)in)[i];
  const float a[4] = {v.x, v.y, v.z, v.w};
  bf16x4 h4, l4;
#pragma unroll
  for (int j = 0; j < 4; j++) {
    bf16 h = (bf16)a[j];
    h4[j] = h;
    l4[j] = (bf16)(a[j] - (float)h);
  }
  ((bf16x4*)hi)[i] = h4;
  ((bf16x4*)lo)[i] = l4;
}

// --------- (x + bias[col]) -> bf16 hi/lo split (K path) ---------------------
__global__ __launch_bounds__(256) void bias_split_k(
    const float* __restrict__ in, const float* __restrict__ bias,
    bf16* __restrict__ hi, bf16* __restrict__ lo)
{
  const size_t i = (size_t)blockIdx.x * 256 + threadIdx.x;  // float4 index
  const float4 v = ((const float4*)in)[i];
  const float4 bb = ((const float4*)bias)[i & (CC / 4 - 1)];
  const float a[4] = {v.x + bb.x, v.y + bb.y, v.z + bb.z, v.w + bb.w};
  bf16x4 h4, l4;
#pragma unroll
  for (int j = 0; j < 4; j++) {
    bf16 h = (bf16)a[j];
    h4[j] = h;
    l4[j] = (bf16)(a[j] - (float)h);
  }
  ((bf16x4*)hi)[i] = h4;
  ((bf16x4*)lo)[i] = l4;
}

// --------- (V + bias) -> transpose to [b,h,d,l] -> bf16 hi/lo split ---------
__global__ __launch_bounds__(256) void bias_split_vt_k(
    const float* __restrict__ Vf, const float* __restrict__ bias,
    bf16* __restrict__ vth, bf16* __restrict__ vtl)
{
  __shared__ float tile[32][33];
  const int t = threadIdx.x;
  const int l0 = blockIdx.x * 32, d0 = blockIdx.y * 32, bh = blockIdx.z;
  const int b = bh >> 4, h = bh & 15;
  const int r = t >> 3, c4 = (t & 7) * 4;
  const float4 v = *(const float4*)&Vf[((size_t)b * CL + l0 + r) * CC + h * CD + d0 + c4];
  const float4 bb = *(const float4*)&bias[h * CD + d0 + c4];
  tile[r][c4 + 0] = v.x + bb.x;
  tile[r][c4 + 1] = v.y + bb.y;
  tile[r][c4 + 2] = v.z + bb.z;
  tile[r][c4 + 3] = v.w + bb.w;
  __syncthreads();
  bf16x4 h4, l4;
#pragma unroll
  for (int j = 0; j < 4; j++) {
    const float a = tile[c4 + j][r];   // transposed read, pad-33 => <=2-way
    const bf16 hh = (bf16)a;
    h4[j] = hh;
    l4[j] = (bf16)(a - (float)hh);
  }
  const size_t o = ((size_t)bh * CD + d0 + r) * CL + l0 + c4;
  *(bf16x4*)&vth[o] = h4;
  *(bf16x4*)&vtl[o] = l4;
}

// --------- int8 GEMM, A[M,K] * B[Nd,K]^T, both K-major, pre-swizzled --------
// MODE: 0 = fp32 out w/ dequant+bias;  1 = dequant+bias then split hi/lo bf16
// 2-phase double-buffered pipeline (one barrier per K-step).
// R7: T1 XCD swizzle — 8 consecutive m-panels per XCD (A slice 2 MiB + whole
// B 4 MiB fit the 4 MiB... A+B hot set L2-resident per XCD).
template <int MODE>
__global__ __launch_bounds__(256) void gemm_i8(
    const signed char* __restrict__ A, const signed char* __restrict__ B,
    float* __restrict__ out0, bf16* __restrict__ outH, bf16* __restrict__ outL,
    const float* __restrict__ rowS, const float* __restrict__ colS,
    const float* __restrict__ bias, const int Nd, const int K)
{
  __shared__ signed char sA[2][128 * 64] __attribute__((aligned(16)));
  __shared__ signed char sB[2][128 * 64] __attribute__((aligned(16)));
  const int t = threadIdx.x;
  int lin = blockIdx.y * 16 + blockIdx.x;          // grid = (16, 64) = 1024
  lin = (lin & 7) * 128 + (lin >> 3);              // XCD-contiguous logical id
  const int m0 = (lin >> 4) * 128, n0 = (lin & 15) * 128;
  const int srow = t >> 2, scol = (t & 3) * 16;   // 64 rows/instr, 16B/lane
  const signed char* aP = A + (size_t)(m0 + srow) * K + scol;
  const signed char* bP = B + (size_t)(n0 + srow) * K + scol;
  const int lane = t & 63, wave = t >> 6;
  const int wm = (wave >> 1) * 64, wn = (wave & 1) * 64;
  const int quad = lane >> 4, l16 = lane & 15;
  i32x4 acc[4][4] = {};

  // prologue: stage k-block 0 into buffer 0
  gl_lds16(aP,                  &sA[0][t * 16]);
  gl_lds16(aP + (size_t)64 * K, &sA[0][4096 + t * 16]);
  gl_lds16(bP,                  &sB[0][t * 16]);
  gl_lds16(bP + (size_t)64 * K, &sB[0][4096 + t * 16]);
  __syncthreads();

  int cur = 0;
  for (int kb = 0; kb < K; kb += 64) {
    const int nx = kb + 64;
    if (nx < K) {   // stage next k-block into the other buffer (async)
      gl_lds16(aP + nx,                  &sA[cur ^ 1][t * 16]);
      gl_lds16(aP + nx + (size_t)64 * K, &sA[cur ^ 1][4096 + t * 16]);
      gl_lds16(bP + nx,                  &sB[cur ^ 1][t * 16]);
      gl_lds16(bP + nx + (size_t)64 * K, &sB[cur ^ 1][4096 + t * 16]);
    }
    i32x4 fa[4], fb[4];
#pragma unroll
    for (int i = 0; i < 4; i++) {
      const int ra = wm + i * 16 + l16;
      const int rb = wn + i * 16 + l16;
      fa[i] = *(const i32x4*)&sA[cur][ra * 64 + (quad ^ ((ra >> 1) & 3)) * 16];
      fb[i] = *(const i32x4*)&sB[cur][rb * 64 + (quad ^ ((rb >> 1) & 3)) * 16];
    }
#pragma unroll
    for (int mt = 0; mt < 4; mt++)
#pragma unroll
      for (int nt = 0; nt < 4; nt++)
        acc[mt][nt] = mfma_i8(fa[mt], fb[nt], acc[mt][nt]);
    __syncthreads();   // drains vmcnt(0): buf^1 staged; lgkm: buf reads done
    cur ^= 1;
  }

  // epilogue: C/D layout col=lane&15, row=quad*4+reg (shape-determined)
#pragma unroll
  for (int mt = 0; mt < 4; mt++)
#pragma unroll
    for (int nt = 0; nt < 4; nt++)
#pragma unroll
      for (int rg = 0; rg < 4; rg++) {
        const int mr = m0 + wm + mt * 16 + quad * 4 + rg;
        const int nc = n0 + wn + nt * 16 + l16;
        const float a = (float)acc[mt][nt][rg];
        const float sc = rowS[mr] * colS[nc];   // (sx*sw) first: matches np
        const float v = a * sc + bias[nc];
        if (MODE == 0) {
          out0[(size_t)mr * Nd + nc] = v;
        } else {
          const bf16 h = (bf16)v;
          outH[(size_t)mr * Nd + nc] = h;
          outL[(size_t)mr * Nd + nc] = (bf16)(v - (float)h);
        }
      }
}

// --------- bf16-split GEMM (K/V projections only) ---------------------------
// TERMS=3 hi/lo split (fp32 emulation), MODE=2 atomic split-K, FUSEKV
// R7: T1 XCD swizzle on the 1024-block grid.
__global__ __launch_bounds__(256) void gemm_kv(
    const bf16* __restrict__ Ah, const bf16* __restrict__ Al,
    const bf16* __restrict__ B0h, const bf16* __restrict__ B0l,
    const bf16* __restrict__ B1h, const bf16* __restrict__ B1l,
    float* __restrict__ out0, float* __restrict__ out1,
    const int Nd, const int K, const int kLen)
{
  __shared__ bf16 sAh[128 * 32] __attribute__((aligned(16)));
  __shared__ bf16 sBh[128 * 32] __attribute__((aligned(16)));
  __shared__ bf16 sAl[128 * 32] __attribute__((aligned(16)));
  __shared__ bf16 sBl[128 * 32] __attribute__((aligned(16)));
  const int t = threadIdx.x;
  int lin = (blockIdx.z * 8 + blockIdx.y) * 16 + blockIdx.x;  // (16,8,8) grid
  lin = (lin & 7) * 128 + (lin >> 3);                         // XCD swizzle
  const int bx = lin & 15, by = (lin >> 4) & 7, bz = lin >> 7;
  const int kv = bz >> 2, chunk = bz & 3;
  const bf16* Bh = kv ? B1h : B0h;
  const bf16* Bl = kv ? B1l : B0l;
  float* outF = kv ? out1 : out0;
  const int m0 = by * 128, n0 = bx * 128;
  const int k0 = chunk * kLen;
  const int srow = t >> 2, scol = (t & 3) * 8;
  const bf16* aP  = Ah + (size_t)(m0 + srow) * K + k0 + scol;
  const bf16* bP  = Bh + (size_t)(n0 + srow) * K + k0 + scol;
  const bf16* aPl = Al + (size_t)(m0 + srow) * K + k0 + scol;
  const bf16* bPl = Bl + (size_t)(n0 + srow) * K + k0 + scol;
  const int lane = t & 63, wave = t >> 6;
  const int wm = (wave >> 1) * 64, wn = (wave & 1) * 64;
  const int quad = lane >> 4, l16 = lane & 15;
  f32x4 acc[4][4] = {};

  for (int kb = 0; kb < kLen; kb += 32) {
    __syncthreads();
    gl_lds16(aP + kb,                   &sAh[t * 8]);
    gl_lds16(aP + kb + (size_t)64 * K,  &sAh[2048 + t * 8]);
    gl_lds16(bP + kb,                   &sBh[t * 8]);
    gl_lds16(bP + kb + (size_t)64 * K,  &sBh[2048 + t * 8]);
    gl_lds16(aPl + kb,                  &sAl[t * 8]);
    gl_lds16(aPl + kb + (size_t)64 * K, &sAl[2048 + t * 8]);
    gl_lds16(bPl + kb,                  &sBl[t * 8]);
    gl_lds16(bPl + kb + (size_t)64 * K, &sBl[2048 + t * 8]);
    __syncthreads();
    bf16x8 fa[4], fb[4], fal[4], fbl[4];
#pragma unroll
    for (int i = 0; i < 4; i++) {
      fa[i]  = *(const bf16x8*)&sAh[(wm + i * 16 + l16) * 32 + quad * 8];
      fb[i]  = *(const bf16x8*)&sBh[(wn + i * 16 + l16) * 32 + quad * 8];
      fal[i] = *(const bf16x8*)&sAl[(wm + i * 16 + l16) * 32 + quad * 8];
      fbl[i] = *(const bf16x8*)&sBl[(wn + i * 16 + l16) * 32 + quad * 8];
    }
#pragma unroll
    for (int mt = 0; mt < 4; mt++)
#pragma unroll
      for (int nt = 0; nt < 4; nt++) {
        f32x4 c = acc[mt][nt];
        c = mfma16(fa[mt],  fb[nt],  c);
        c = mfma16(fa[mt],  fbl[nt], c);
        c = mfma16(fal[mt], fb[nt],  c);
        acc[mt][nt] = c;
      }
  }

#pragma unroll
  for (int mt = 0; mt < 4; mt++)
#pragma unroll
    for (int nt = 0; nt < 4; nt++)
#pragma unroll
      for (int rg = 0; rg < 4; rg++) {
        const int mr = m0 + wm + mt * 16 + quad * 4 + rg;
        const int nc = n0 + wn + nt * 16 + l16;
        atomicAdd(&outF[(size_t)mr * Nd + nc], acc[mt][nt][rg]);
      }
}

// --------- flash attention, split-bf16, MAX-FREE softmax --------------------
// block = 512 thr / 8 waves / 128 Q rows; wave owns 16 rows.
// R7: register diet for 2 blocks/CU — mask loaded per-chunk at chunk top
// (QK's ~400cy covers it; no double-buffer), K prefetch at chunk top, V
// prefetch post-softmax (staggered lifetimes).  launch_bounds(512,4) caps
// total regs at 128 => 16 waves/CU.  T1 XCD swizzle: 4 (b,h) K/V panels
// (2 MiB) per XCD => L2-resident.
__global__ __launch_bounds__(512, 4) void attn_k(
    const bf16* __restrict__ qh, const bf16* __restrict__ ql,
    const bf16* __restrict__ kh, const bf16* __restrict__ kl,
    const bf16* __restrict__ vth, const bf16* __restrict__ vtl,
    const float* __restrict__ mask, float* __restrict__ O)
{
  // arena: ks [2][32][136] (17408 B) | vt [2][128][40] (20480 B) | ps [8][16][36] (18432 B)
  __shared__ char arena[17408 + 20480 + 18432] __attribute__((aligned(16)));
  bf16 (*ks)[32][136] = (bf16 (*)[32][136])arena;
  bf16 (*vt)[128][40] = (bf16 (*)[128][40])(arena + 17408);
  float (*ps)[16][36] = (float (*)[16][36])(arena + 17408 + 20480);
  const int t = threadIdx.x, lane = t & 63, w = t >> 6;
  const int quad = lane >> 4, l16 = lane & 15;
  int lin = (blockIdx.z * 16 + blockIdx.y) * 32 + blockIdx.x;  // (32,16,2)
  lin = (lin & 7) * 128 + (lin >> 3);                          // XCD swizzle
  const int n0 = (lin & 31) * 128;
  const int h  = (lin >> 5) & 15;
  const int b  = lin >> 9;
  const int bh = b * CH + h;
  const size_t qrow0 = (size_t)b * CN + n0;
  const float* mrow_base = mask + ((size_t)b * CN + n0 + w * 16 + quad * 4) * CL;

  // ---- staging-lane geometry + chunk-0 K/V prefetch (overlaps Q staging) ---
  const int krow = t >> 4, ksg = t & 15;   // K: 32 l-rows x 128 d, 16B/lane
  const int vrow = t >> 2, vsg = t & 3;    // V^T: 128 d-rows x 32 l, 16B/lane
  uint4 krh, krl, vrh, vrl;
  {
    const size_t gro = ((size_t)b * CL + krow) * CC + h * CD + ksg * 8;
    krh = *(const uint4*)(kh + gro);
    krl = *(const uint4*)(kl + gro);
    const size_t gvo = ((size_t)bh * CD + vrow) * CL + vsg * 8;
    vrh = *(const uint4*)(vth + gvo);
    vrl = *(const uint4*)(vtl + gvo);
  }

  // ---- Q fragments into registers (staged via arena for coalescing) ----
  bf16x8 qfh[4], qfl[4];
  {
    bf16* qs = (bf16*)arena;   // 128 rows x 136 = 34816 B <= ks+vt extent
    const int row = t >> 2, sg = t & 3;
    {
      const bf16* src = qh + (qrow0 + row) * CC + h * CD + sg * 32;
      bf16* dst = qs + row * 136 + sg * 32;
#pragma unroll
      for (int j = 0; j < 4; j++) ((uint4*)dst)[j] = ((const uint4*)src)[j];
    }
    __syncthreads();
#pragma unroll
    for (int s = 0; s < 4; s++)
      qfh[s] = *(const bf16x8*)&qs[(w * 16 + l16) * 136 + s * 32 + quad * 8];
    __syncthreads();
    {
      const bf16* src = ql + (qrow0 + row) * CC + h * CD + sg * 32;
      bf16* dst = qs + row * 136 + sg * 32;
#pragma unroll
      for (int j = 0; j < 4; j++) ((uint4*)dst)[j] = ((const uint4*)src)[j];
    }
    __syncthreads();
#pragma unroll
    for (int s = 0; s < 4; s++)
      qfl[s] = *(const bf16x8*)&qs[(w * 16 + l16) * 136 + s * 32 + quad * 8];
  }

  f32x4 oacc[8] = {};
  f32x4 suma = {};          // row-sum accumulator (MFMA ones-trick)
  const bf16 one = (bf16)1.0f;
  const bf16x8 ones = {one, one, one, one, one, one, one, one};
  const float isd = 0.08838834764831845f;   // np.float32(1/sqrt(128))

  for (int lc = 0; lc < CL; lc += 32) {
    __syncthreads();   // prior chunk's frag reads done (buffers free)
    // ---- write-late: ds_write the prefetched (already landed) registers ---
    *(uint4*)&ks[0][krow][ksg * 8] = krh;
    *(uint4*)&ks[1][krow][ksg * 8] = krl;
    {
      const int vc = (vsg ^ ((vrow >> 3) & 3)) * 8;   // XOR chunk swizzle
      *(uint4*)&vt[0][vrow][vc] = vrh;
      *(uint4*)&vt[1][vrow][vc] = vrl;
    }
    __syncthreads();

    // ---- current-chunk mask loads (QK's ~400cy covers the latency) --------
    float mcur[2][4];
#pragma unroll
    for (int rg = 0; rg < 4; rg++) {
      const float* mrp = mrow_base + (size_t)rg * CL + lc;
      mcur[0][rg] = mrp[l16];
      mcur[1][rg] = mrp[16 + l16];
    }
    // ---- issue-early: next-chunk K prefetch (consumed at next loop top) ---
    const int lcn = lc + 32;
    if (lcn < CL) {
      const size_t gro = ((size_t)b * CL + lcn + krow) * CC + h * CD + ksg * 8;
      krh = *(const uint4*)(kh + gro);
      krl = *(const uint4*)(kl + gro);
    }

    // ---- S = Q K^T (split, 3 terms), two 16x16 l-tiles -------------------
    f32x4 sacc[2] = {};
    __builtin_amdgcn_s_setprio(1);
#pragma unroll
    for (int s = 0; s < 4; s++) {
#pragma unroll
      for (int lt = 0; lt < 2; lt++) {
        bf16x8 kbh = *(const bf16x8*)&ks[0][lt * 16 + l16][s * 32 + quad * 8];
        bf16x8 kbl = *(const bf16x8*)&ks[1][lt * 16 + l16][s * 32 + quad * 8];
        sacc[lt] = mfma16(qfh[s], kbh, sacc[lt]);
        sacc[lt] = mfma16(qfh[s], kbl, sacc[lt]);
        sacc[lt] = mfma16(qfl[s], kbh, sacc[lt]);
      }
    }
    __builtin_amdgcn_s_setprio(0);

    // ---- MAX-FREE softmax: u = exp(s*isd + mask); sum rides MFMA ---------
    float u[2][4];
#pragma unroll
    for (int rg = 0; rg < 4; rg++) {
      u[0][rg] = __expf(sacc[0][rg] * isd + mcur[0][rg]);
      u[1][rg] = __expf(sacc[1][rg] * isd + mcur[1][rg]);
    }

    // ---- issue-early: next-chunk V prefetch (PV's ~400cy covers it) ------
    if (lcn < CL) {
      const size_t gvo = ((size_t)bh * CD + vrow) * CL + lcn + vsg * 8;
      vrh = *(const uint4*)(vth + gvo);
      vrl = *(const uint4*)(vtl + gvo);
    }

    // ---- P: C-layout -> A-layout via wave-private LDS round-trip ---------
#pragma unroll
    for (int lt = 0; lt < 2; lt++)
#pragma unroll
      for (int rg = 0; rg < 4; rg++)
        ps[w][quad * 4 + rg][lt * 16 + l16] = u[lt][rg];
    const float4 p0 = *(const float4*)&ps[w][l16][quad * 8];
    const float4 p1 = *(const float4*)&ps[w][l16][quad * 8 + 4];
    const float pv[8] = {p0.x, p0.y, p0.z, p0.w, p1.x, p1.y, p1.z, p1.w};
    bf16x8 ph, pl;
#pragma unroll
    for (int j = 0; j < 8; j++) {
      bf16 hh = (bf16)pv[j];
      ph[j] = hh;
      pl[j] = (bf16)(pv[j] - (float)hh);
    }

    // ---- O += P V (split, 3 terms) + row-sum channel ---------------------
    suma = mfma16(ph, ones, suma);
    suma = mfma16(pl, ones, suma);
    __builtin_amdgcn_s_setprio(1);
#pragma unroll
    for (int nt = 0; nt < 8; nt++) {
      const int vr = nt * 16 + l16;
      const int vsw = (quad ^ ((vr >> 3) & 3)) * 8;   // match staging swizzle
      bf16x8 vbh = *(const bf16x8*)&vt[0][vr][vsw];
      bf16x8 vbl = *(const bf16x8*)&vt[1][vr][vsw];
      f32x4 c = oacc[nt];
      c = mfma16(ph, vbh, c);
      c = mfma16(ph, vbl, c);
      c = mfma16(pl, vbh, c);
      oacc[nt] = c;
    }
    __builtin_amdgcn_s_setprio(0);
  }

  // ---- epilogue: O / sum ----------------------------------------------------
  f32x4 inv;
#pragma unroll
  for (int rg = 0; rg < 4; rg++) inv[rg] = 1.0f / suma[rg];
#pragma unroll
  for (int nt = 0; nt < 8; nt++)
#pragma unroll
    for (int rg = 0; rg < 4; rg++) {
      const size_t row = qrow0 + w * 16 + quad * 4 + rg;
      O[row * CC + h * CD + nt * 16 + l16] = oacc[nt][rg] * inv[rg];
    }
}

// ---------------------------------------------------------------------------
extern "C" void kernel_launch(void* const* d_in, const int* in_sizes, int n_in,
                              void* d_out, int out_size, void* d_ws, size_t ws_size,
                              hipStream_t stream)
{
  (void)in_sizes; (void)n_in; (void)out_size; (void)ws_size;
  const float* x    = (const float*)d_in[0];
  const float* cond = (const float*)d_in[1];
  const float* mask = (const float*)d_in[2];
  const float* wq   = (const float*)d_in[3];
  const float* bq   = (const float*)d_in[4];
  const float* wk   = (const float*)d_in[5];
  const float* bk   = (const float*)d_in[6];
  const float* wv   = (const float*)d_in[7];
  const float* bv   = (const float*)d_in[8];
  const float* wo   = (const float*)d_in[9];
  const float* bo   = (const float*)d_in[10];
  float* out = (float*)d_out;

  char* wsb = (char*)d_ws;
  size_t off = 0;
  auto alloc = [&](size_t bytes) -> char* {
    char* p = wsb + off;
    off += (bytes + 255) & ~(size_t)255;
    return p;
  };
  // Region 1 (dead before attention; Obuf 64 MiB aliases qx..Kf)
  signed char* qx  = (signed char*)alloc((size_t)TOK * CC);  // 16 MiB
  signed char* qwq = (signed char*)alloc((size_t)CC * CC);   //  4 MiB
  bf16* ch  = (bf16*)alloc((size_t)LR * CC * 2);   //  4 MiB
  bf16* cl_ = (bf16*)alloc((size_t)LR * CC * 2);   //  4 MiB
  bf16* wkh = (bf16*)alloc((size_t)CC * CC * 2);   //  8 MiB
  bf16* wkl = (bf16*)alloc((size_t)CC * CC * 2);   //  8 MiB
  bf16* wvh = (bf16*)alloc((size_t)CC * CC * 2);   //  8 MiB
  bf16* wvl = (bf16*)alloc((size_t)CC * CC * 2);   //  8 MiB
  float* Kf = (float*)alloc((size_t)LR * CC * 4);  //  8 MiB (split-K accum)
  float* Vf = (float*)alloc((size_t)LR * CC * 4);  //  8 MiB (contiguous after Kf)
  float* Obuf = (float*)qx;                        // alias: 64 MiB over qx..Kf
  // Region 2 (live through attention)
  bf16* qhb = (bf16*)alloc((size_t)TOK * CC * 2);  // 32 MiB (later reused as qO)
  bf16* qlb = (bf16*)alloc((size_t)TOK * CC * 2);  // 32 MiB
  bf16* khb = (bf16*)alloc((size_t)LR * CC * 2);
  bf16* klb = (bf16*)alloc((size_t)LR * CC * 2);
  bf16* vth = (bf16*)alloc((size_t)LR * CC * 2);   // V^T [b,h,d,l] hi
  bf16* vtl = (bf16*)alloc((size_t)LR * CC * 2);   // V^T [b,h,d,l] lo
  signed char* qwo = (signed char*)alloc((size_t)CC * CC);
  float* sx  = (float*)alloc((size_t)TOK * 4);
  float* swq = (float*)alloc((size_t)CC * 4);
  float* swo = (float*)alloc((size_t)CC * 4);
  float* sO  = (float*)alloc((size_t)TOK * 4);
  signed char* qO = (signed char*)qhb;   // alias: qh/ql dead after attention

  // 1) quantize weights and x (int8, swizzled for gemm_i8)
  quant_rows_i8<<<CC,  256, 0, stream>>>(wq, qwq, swq);
  quant_rows_i8<<<CC,  256, 0, stream>>>(wo, qwo, swo);
  quant_rows_i8<<<TOK, 256, 0, stream>>>(x, qx, sx);
  // 2) split fp32 inputs for the fp32-emulated GEMMs
  split_pair_k<<<(LR * CC / 4) / 256, 256, 0, stream>>>(cond, ch, cl_);
  split_pair_k<<<(CC * CC / 4) / 256, 256, 0, stream>>>(wk, wkh, wkl);
  split_pair_k<<<(CC * CC / 4) / 256, 256, 0, stream>>>(wv, wvh, wvl);
  // 3) Q = dequant(qx @ qwq^T) + bq, written as bf16 hi/lo split  (i8 MFMA)
  gemm_i8<1><<<dim3(CC / 128, TOK / 128, 1), 256, 0, stream>>>(
      qx, qwq, nullptr, qhb, qlb, sx, swq, bq, CC, CC);
  // 4) K/V projections: fused-KV + split-K x4 (atomic fp32 accum)
  (void)hipMemsetAsync(Kf, 0, (size_t)LR * CC * 4 * 2, stream);  // Kf+Vf contiguous
  gemm_kv<<<dim3(CC / 128, LR / 128, 8), 256, 0, stream>>>(
      ch, cl_, wkh, wkl, wvh, wvl, Kf, Vf, CC, CC, 512);
  bias_split_k<<<(LR * CC / 4) / 256, 256, 0, stream>>>(Kf, bk, khb, klb);
  bias_split_vt_k<<<dim3(CL / 32, CD / 32, CB * CH), 256, 0, stream>>>(Vf, bv, vth, vtl);
  // 5) attention: 128-row Q tiles, 512 threads, max-free softmax
  attn_k<<<dim3(CN / 128, CH, CB), 512, 0, stream>>>(
      qhb, qlb, khb, klb, vth, vtl, mask, Obuf);
  // 6) requant O (int8 swizzled), then output projection (i8 MFMA)
  quant_rows_i8<<<TOK, 256, 0, stream>>>(Obuf, qO, sO);
  gemm_i8<0><<<dim3(CC / 128, TOK / 128, 1), 256, 0, stream>>>(
      qO, qwo, out, nullptr, nullptr, sO, swo, bo, CC, CC);
}